// Round 6
// baseline (715.595 us; speedup 1.0000x reference)
//
#include <hip/hip_runtime.h>
#include <math.h>

// N=1M nodes, E=32M edges. Counting-sort edges by dst-bucket (256 bins x 4096
// nodes), then both aggregation passes use LDS atomics only.
// R6: agg occupancy fix — R5's agg grid was NB=245 blocks (<256 CUs, 1
// block/CU, 44% occupancy, latency-bound on random m[src] gathers). Now each
// bin is split across S=4 sub-blocks (grid 980, 512 thr, 16KB LDS -> 4
// blocks/CU, 32 waves/CU); sub-blocks store 16KB partial arrays (plain
// stores), tiny combine kernels reduce them.
//
// record = (src << 12) | (dst & 4095)   [src < 2^20]
// ws: m (4MB) | gcur | cls (1MB) | part (NB*S*16KB ~16MB) | gsorted (~132MB)

#define EPS 1e-15f
#define CHUNK 8192
#define PTHREADS 512
#define NBINS 256
#define BNODES 4096
#define SPLIT 4

typedef int          vint4  __attribute__((ext_vector_type(4)));
typedef unsigned int vuint4 __attribute__((ext_vector_type(4)));

// ===================== common prep =====================

__global__ __launch_bounds__(256)
void k_prep2(const float2* __restrict__ x, const float* __restrict__ W,
             float* __restrict__ m, unsigned int* __restrict__ gcur,
             int N, int NB, unsigned int CAP) {
    int i = blockIdx.x * 256 + threadIdx.x;
    if (i < N) {
        float2 v = x[i];
        float inv = 1.0f / (sqrtf(v.x * v.x + v.y * v.y) + EPS);
        m[i] = (v.x * inv) * W[0] + (v.y * inv) * W[2];
    }
    if (i < NB) gcur[i] = (unsigned)i * CAP;
}

// ===================== permute (unchanged from R5) =====================

__global__ __launch_bounds__(PTHREADS)
void k_permute(const int* __restrict__ src, const int* __restrict__ dst,
               unsigned int* __restrict__ gsorted, unsigned int* __restrict__ gcur,
               int E) {
    __shared__ unsigned int  sh_sorted[CHUNK];   // 32 KB
    __shared__ unsigned char sh_bin[CHUNK];      //  8 KB
    __shared__ unsigned int  sh_hist[NBINS];
    __shared__ unsigned int  sh_loff[NBINS];
    __shared__ unsigned int  sh_delta[NBINS];
    __shared__ unsigned int  sh_scan[NBINS];
    const int tid = threadIdx.x;
    const long long e0 = (long long)blockIdx.x * CHUNK;
    const int n = (int)min((long long)CHUNK, (long long)E - e0);
    const int nv4 = (n >> 2) << 2;

    if (tid < NBINS) sh_hist[tid] = 0u;
    __syncthreads();

    #pragma unroll
    for (int k = 0; k < CHUNK / (PTHREADS * 4); ++k) {
        int o = (k * PTHREADS + tid) * 4;
        if (o < nv4) {
            vint4 d = *(const vint4*)(dst + e0 + o);
            atomicAdd(&sh_hist[((unsigned)d.x) >> 12], 1u);
            atomicAdd(&sh_hist[((unsigned)d.y) >> 12], 1u);
            atomicAdd(&sh_hist[((unsigned)d.z) >> 12], 1u);
            atomicAdd(&sh_hist[((unsigned)d.w) >> 12], 1u);
        }
    }
    for (int j = nv4 + tid; j < n; j += PTHREADS)
        atomicAdd(&sh_hist[((unsigned)dst[e0 + j]) >> 12], 1u);
    __syncthreads();

    if (tid < NBINS) sh_scan[tid] = sh_hist[tid];
    __syncthreads();
    for (int off = 1; off < NBINS; off <<= 1) {
        unsigned v = 0;
        if (tid < NBINS && tid >= off) v = sh_scan[tid - off];
        __syncthreads();
        if (tid < NBINS) sh_scan[tid] += v;
        __syncthreads();
    }
    if (tid < NBINS) {
        unsigned h = sh_hist[tid];
        unsigned lo = sh_scan[tid] - h;
        sh_loff[tid] = lo;
        if (h) sh_delta[tid] = atomicAdd(&gcur[tid], h) - lo;
    }
    __syncthreads();
    if (tid < NBINS) sh_hist[tid] = sh_loff[tid];
    __syncthreads();

    #pragma unroll
    for (int k = 0; k < CHUNK / (PTHREADS * 4); ++k) {
        int o = (k * PTHREADS + tid) * 4;
        if (o < nv4) {
            vint4 s = __builtin_nontemporal_load((const vint4*)(src + e0 + o));
            vint4 d = *(const vint4*)(dst + e0 + o);
            unsigned b, p;
            b = ((unsigned)d.x) >> 12; p = atomicAdd(&sh_hist[b], 1u);
            sh_sorted[p] = ((unsigned)s.x << 12) | ((unsigned)d.x & 4095u); sh_bin[p] = (unsigned char)b;
            b = ((unsigned)d.y) >> 12; p = atomicAdd(&sh_hist[b], 1u);
            sh_sorted[p] = ((unsigned)s.y << 12) | ((unsigned)d.y & 4095u); sh_bin[p] = (unsigned char)b;
            b = ((unsigned)d.z) >> 12; p = atomicAdd(&sh_hist[b], 1u);
            sh_sorted[p] = ((unsigned)s.z << 12) | ((unsigned)d.z & 4095u); sh_bin[p] = (unsigned char)b;
            b = ((unsigned)d.w) >> 12; p = atomicAdd(&sh_hist[b], 1u);
            sh_sorted[p] = ((unsigned)s.w << 12) | ((unsigned)d.w & 4095u); sh_bin[p] = (unsigned char)b;
        }
    }
    for (int j = nv4 + tid; j < n; j += PTHREADS) {
        unsigned dv = (unsigned)dst[e0 + j], sv = (unsigned)src[e0 + j];
        unsigned b = dv >> 12;
        unsigned p = atomicAdd(&sh_hist[b], 1u);
        sh_sorted[p] = (sv << 12) | (dv & 4095u);
        sh_bin[p] = (unsigned char)b;
    }
    __syncthreads();

    for (int t = tid; t < n; t += PTHREADS)
        gsorted[sh_delta[sh_bin[t]] + (unsigned)t] = sh_sorted[t];
}

// ===================== split aggregation (R6) =====================

// pass-1 sub-block: partial y sums for bin b over segment s.
__global__ __launch_bounds__(512)
void k_agg1s(const unsigned int* __restrict__ gsorted, const unsigned int* __restrict__ gcur,
             const float* __restrict__ m, float* __restrict__ ypart, unsigned int CAP) {
    __shared__ float yloc[BNODES];   // 16 KB
    const int tid = threadIdx.x;
    const int b = blockIdx.x / SPLIT;
    const int s = blockIdx.x % SPLIT;
    for (int j = tid; j < BNODES; j += 512) yloc[j] = 0.0f;
    __syncthreads();
    const unsigned base = (unsigned)b * CAP;
    const unsigned cnt = gcur[b] - base;
    const unsigned seg = (((cnt + SPLIT - 1) / SPLIT) + 7u) & ~7u;
    const unsigned start = s * seg;
    const unsigned end = min(start + seg, cnt);
    if (start < end) {
        const unsigned len = end - start;
        const unsigned pairs = len >> 3;           // 8 records per thread-iter
        const vuint4* pv = (const vuint4*)(gsorted + base + start);
        for (unsigned p = tid; p < pairs; p += 512) {
            vuint4 a = pv[2 * p];
            vuint4 c = pv[2 * p + 1];
            float g0 = m[a.x >> 12], g1 = m[a.y >> 12], g2 = m[a.z >> 12], g3 = m[a.w >> 12];
            float g4 = m[c.x >> 12], g5 = m[c.y >> 12], g6 = m[c.z >> 12], g7 = m[c.w >> 12];
            atomicAdd(&yloc[a.x & 4095u], g0);
            atomicAdd(&yloc[a.y & 4095u], g1);
            atomicAdd(&yloc[a.z & 4095u], g2);
            atomicAdd(&yloc[a.w & 4095u], g3);
            atomicAdd(&yloc[c.x & 4095u], g4);
            atomicAdd(&yloc[c.y & 4095u], g5);
            atomicAdd(&yloc[c.z & 4095u], g6);
            atomicAdd(&yloc[c.w & 4095u], g7);
        }
        for (unsigned i = start + (pairs << 3) + tid; i < end; i += 512) {
            unsigned p = gsorted[base + i];
            atomicAdd(&yloc[p & 4095u], m[p >> 12]);
        }
    }
    __syncthreads();
    float* dstp = ypart + ((size_t)blockIdx.x << 12);
    for (int j = tid; j < BNODES; j += 512) dstp[j] = yloc[j];
}

// combine pass-1 partials -> cls
__global__ __launch_bounds__(256)
void k_comb1(const float* __restrict__ ypart, unsigned char* __restrict__ cls, int N) {
    int node = blockIdx.x * 256 + threadIdx.x;
    if (node < N) {
        int b = node >> 12, j = node & 4095;
        float v = 0.0f;
        #pragma unroll
        for (int s = 0; s < SPLIT; ++s)
            v += ypart[(((size_t)b * SPLIT + s) << 12) + j];
        cls[node] = (v > 0.0f) ? 1 : ((v < 0.0f) ? 2 : 0);
    }
}

// pass-2 sub-block: partial packed counts for bin b over segment s.
__global__ __launch_bounds__(512)
void k_agg2s(const unsigned int* __restrict__ gsorted, const unsigned int* __restrict__ gcur,
             const unsigned char* __restrict__ cls, unsigned int* __restrict__ pkpart,
             unsigned int CAP) {
    __shared__ unsigned int pkloc[BNODES];   // 16 KB
    const int tid = threadIdx.x;
    const int b = blockIdx.x / SPLIT;
    const int s = blockIdx.x % SPLIT;
    for (int j = tid; j < BNODES; j += 512) pkloc[j] = 0u;
    __syncthreads();
    const unsigned base = (unsigned)b * CAP;
    const unsigned cnt = gcur[b] - base;
    const unsigned seg = (((cnt + SPLIT - 1) / SPLIT) + 7u) & ~7u;
    const unsigned start = s * seg;
    const unsigned end = min(start + seg, cnt);
    auto dec = [](unsigned char c) -> unsigned int {
        return (c == 1) ? 65536u : ((c == 2) ? 1u : 0u);
    };
    if (start < end) {
        const unsigned len = end - start;
        const unsigned pairs = len >> 3;
        const vuint4* pv = (const vuint4*)(gsorted + base + start);
        for (unsigned p = tid; p < pairs; p += 512) {
            vuint4 a = pv[2 * p];
            vuint4 c = pv[2 * p + 1];
            unsigned char e0 = cls[a.x >> 12], e1 = cls[a.y >> 12], e2 = cls[a.z >> 12], e3 = cls[a.w >> 12];
            unsigned char e4 = cls[c.x >> 12], e5 = cls[c.y >> 12], e6 = cls[c.z >> 12], e7 = cls[c.w >> 12];
            atomicAdd(&pkloc[a.x & 4095u], dec(e0));
            atomicAdd(&pkloc[a.y & 4095u], dec(e1));
            atomicAdd(&pkloc[a.z & 4095u], dec(e2));
            atomicAdd(&pkloc[a.w & 4095u], dec(e3));
            atomicAdd(&pkloc[c.x & 4095u], dec(e4));
            atomicAdd(&pkloc[c.y & 4095u], dec(e5));
            atomicAdd(&pkloc[c.z & 4095u], dec(e6));
            atomicAdd(&pkloc[c.w & 4095u], dec(e7));
        }
        for (unsigned i = start + (pairs << 3) + tid; i < end; i += 512) {
            unsigned p = gsorted[base + i];
            atomicAdd(&pkloc[p & 4095u], dec(cls[p >> 12]));
        }
    }
    __syncthreads();
    unsigned int* dstp = pkpart + ((size_t)blockIdx.x << 12);
    for (int j = tid; j < BNODES; j += 512) dstp[j] = pkloc[j];
}

// combine pass-2 partials -> final output
__global__ __launch_bounds__(256)
void k_comb2(const unsigned int* __restrict__ pkpart, const float* __restrict__ W,
             const float* __restrict__ fw, float* __restrict__ out, int N) {
    int node = blockIdx.x * 256 + threadIdx.x;
    if (node < N) {
        int b = node >> 12, j = node & 4095;
        unsigned p = 0u;
        #pragma unroll
        for (int s = 0; s < SPLIT; ++s)
            p += pkpart[(((size_t)b * SPLIT + s) << 12) + j];
        float c0 = (float)(p >> 16);
        float c1 = (float)(p & 0xFFFFu);
        float x0 = fmaxf(c0 * W[0] + c1 * W[2], 0.0f);
        float x1 = fmaxf(c0 * W[1] + c1 * W[3], 0.0f);
        float z = x0 * fw[0] + x1 * fw[1];
        out[node] = 1.0f / (1.0f + expf(-z));
    }
}

// ===================== monolithic aggs (R5 fallback, ws-tight) =====================

__global__ __launch_bounds__(1024)
void k_agg1(const unsigned int* __restrict__ gsorted, const unsigned int* __restrict__ gcur,
            const float* __restrict__ m, unsigned char* __restrict__ cls,
            int N, unsigned int CAP) {
    __shared__ float yloc[BNODES];
    const int tid = threadIdx.x;
    const int b = blockIdx.x;
    for (int j = tid; j < BNODES; j += 1024) yloc[j] = 0.0f;
    __syncthreads();
    const unsigned base = (unsigned)b * CAP;
    const unsigned cnt = gcur[b] - base;
    const unsigned nv = cnt >> 2;
    const vuint4* pv = (const vuint4*)(gsorted + base);
    for (unsigned k = tid; k < nv; k += 1024) {
        vuint4 p = pv[k];
        atomicAdd(&yloc[p.x & 4095u], m[p.x >> 12]);
        atomicAdd(&yloc[p.y & 4095u], m[p.y >> 12]);
        atomicAdd(&yloc[p.z & 4095u], m[p.z >> 12]);
        atomicAdd(&yloc[p.w & 4095u], m[p.w >> 12]);
    }
    for (unsigned i = (nv << 2) + tid; i < cnt; i += 1024) {
        unsigned p = gsorted[base + i];
        atomicAdd(&yloc[p & 4095u], m[p >> 12]);
    }
    __syncthreads();
    for (int j = tid; j < BNODES; j += 1024) {
        int node = b * BNODES + j;
        if (node < N) {
            float v = yloc[j];
            cls[node] = (v > 0.0f) ? 1 : ((v < 0.0f) ? 2 : 0);
        }
    }
}

__global__ __launch_bounds__(1024)
void k_agg2(const unsigned int* __restrict__ gsorted, const unsigned int* __restrict__ gcur,
            const unsigned char* __restrict__ cls, const float* __restrict__ W,
            const float* __restrict__ fw, float* __restrict__ out,
            int N, unsigned int CAP) {
    __shared__ unsigned int pkloc[BNODES];
    const int tid = threadIdx.x;
    const int b = blockIdx.x;
    for (int j = tid; j < BNODES; j += 1024) pkloc[j] = 0u;
    __syncthreads();
    const unsigned base = (unsigned)b * CAP;
    const unsigned cnt = gcur[b] - base;
    const unsigned nv = cnt >> 2;
    const vuint4* pv = (const vuint4*)(gsorted + base);
    auto dec = [](unsigned char c) -> unsigned int {
        return (c == 1) ? 65536u : ((c == 2) ? 1u : 0u);
    };
    for (unsigned k = tid; k < nv; k += 1024) {
        vuint4 p = pv[k];
        atomicAdd(&pkloc[p.x & 4095u], dec(cls[p.x >> 12]));
        atomicAdd(&pkloc[p.y & 4095u], dec(cls[p.y >> 12]));
        atomicAdd(&pkloc[p.z & 4095u], dec(cls[p.z >> 12]));
        atomicAdd(&pkloc[p.w & 4095u], dec(cls[p.w >> 12]));
    }
    for (unsigned i = (nv << 2) + tid; i < cnt; i += 1024) {
        unsigned p = gsorted[base + i];
        atomicAdd(&pkloc[p & 4095u], dec(cls[p >> 12]));
    }
    __syncthreads();
    for (int j = tid; j < BNODES; j += 1024) {
        int node = b * BNODES + j;
        if (node < N) {
            unsigned p = pkloc[j];
            float c0 = (float)(p >> 16);
            float c1 = (float)(p & 0xFFFFu);
            float x0 = fmaxf(c0 * W[0] + c1 * W[2], 0.0f);
            float x1 = fmaxf(c0 * W[1] + c1 * W[3], 0.0f);
            float z = x0 * fw[0] + x1 * fw[1];
            out[node] = 1.0f / (1.0f + expf(-z));
        }
    }
}

// ===================== fallback path (R3, atomic-based) =====================

__global__ __launch_bounds__(256)
void k_prep(const float2* __restrict__ x, const float* __restrict__ W,
            float* __restrict__ m, float* __restrict__ y,
            unsigned int* __restrict__ pk, int N) {
    int i = blockIdx.x * blockDim.x + threadIdx.x;
    if (i < N) {
        float2 v = x[i];
        float inv = 1.0f / (sqrtf(v.x * v.x + v.y * v.y) + EPS);
        m[i]  = (v.x * inv) * W[0] + (v.y * inv) * W[2];
        y[i]  = 0.0f;
        pk[i] = 0u;
    }
}

__global__ __launch_bounds__(256)
void k_scatter1(const int* __restrict__ src, const int* __restrict__ dst,
                const float* __restrict__ m, float* __restrict__ y, int E) {
    int t = blockIdx.x * blockDim.x + threadIdx.x;
    int i = t * 8;
    if (i + 8 <= E) {
        vint4 s0 = __builtin_nontemporal_load((const vint4*)(src + i));
        vint4 s1 = __builtin_nontemporal_load((const vint4*)(src + i + 4));
        vint4 d0 = __builtin_nontemporal_load((const vint4*)(dst + i));
        vint4 d1 = __builtin_nontemporal_load((const vint4*)(dst + i + 4));
        unsafeAtomicAdd(&y[d0.x], m[s0.x]);
        unsafeAtomicAdd(&y[d0.y], m[s0.y]);
        unsafeAtomicAdd(&y[d0.z], m[s0.z]);
        unsafeAtomicAdd(&y[d0.w], m[s0.w]);
        unsafeAtomicAdd(&y[d1.x], m[s1.x]);
        unsafeAtomicAdd(&y[d1.y], m[s1.y]);
        unsafeAtomicAdd(&y[d1.z], m[s1.z]);
        unsafeAtomicAdd(&y[d1.w], m[s1.w]);
    } else if (i < E) {
        for (int j = i; j < E; ++j)
            unsafeAtomicAdd(&y[dst[j]], m[src[j]]);
    }
}

__global__ __launch_bounds__(256)
void k_classify(const float* __restrict__ y, unsigned char* __restrict__ cls, int N) {
    int i = blockIdx.x * blockDim.x + threadIdx.x;
    if (i < N) {
        float v = y[i];
        cls[i] = (v > 0.0f) ? 1 : ((v < 0.0f) ? 2 : 0);
    }
}

__global__ __launch_bounds__(256)
void k_scatter2(const int* __restrict__ src, const int* __restrict__ dst,
                const unsigned char* __restrict__ cls, unsigned int* __restrict__ pk,
                int E) {
    int t = blockIdx.x * blockDim.x + threadIdx.x;
    int i = t * 8;
    auto dec = [](unsigned char c) -> unsigned int {
        return (c == 1) ? 65536u : ((c == 2) ? 1u : 0u);
    };
    if (i + 8 <= E) {
        vint4 s0 = __builtin_nontemporal_load((const vint4*)(src + i));
        vint4 s1 = __builtin_nontemporal_load((const vint4*)(src + i + 4));
        vint4 d0 = __builtin_nontemporal_load((const vint4*)(dst + i));
        vint4 d1 = __builtin_nontemporal_load((const vint4*)(dst + i + 4));
        atomicAdd(&pk[d0.x], dec(cls[s0.x]));
        atomicAdd(&pk[d0.y], dec(cls[s0.y]));
        atomicAdd(&pk[d0.z], dec(cls[s0.z]));
        atomicAdd(&pk[d0.w], dec(cls[s0.w]));
        atomicAdd(&pk[d1.x], dec(cls[s1.x]));
        atomicAdd(&pk[d1.y], dec(cls[s1.y]));
        atomicAdd(&pk[d1.z], dec(cls[s1.z]));
        atomicAdd(&pk[d1.w], dec(cls[s1.w]));
    } else if (i < E) {
        for (int j = i; j < E; ++j)
            atomicAdd(&pk[dst[j]], dec(cls[src[j]]));
    }
}

__global__ __launch_bounds__(256)
void k_final(const unsigned int* __restrict__ pk, const float* __restrict__ W,
             const float* __restrict__ fw, float* __restrict__ out, int N) {
    int i = blockIdx.x * blockDim.x + threadIdx.x;
    if (i < N) {
        unsigned p = pk[i];
        float c0 = (float)(p >> 16);
        float c1 = (float)(p & 0xFFFFu);
        float x0 = fmaxf(c0 * W[0] + c1 * W[2], 0.0f);
        float x1 = fmaxf(c0 * W[1] + c1 * W[3], 0.0f);
        float z = x0 * fw[0] + x1 * fw[1];
        out[i] = 1.0f / (1.0f + expf(-z));
    }
}

// ===================== launch =====================

extern "C" void kernel_launch(void* const* d_in, const int* in_sizes, int n_in,
                              void* d_out, int out_size, void* d_ws, size_t ws_size,
                              hipStream_t stream) {
    const float* x  = (const float*)d_in[0];
    const int*   ei = (const int*)d_in[1];
    const float* W  = (const float*)d_in[2];
    const float* fw = (const float*)d_in[3];
    float*       out = (float*)d_out;

    const int N = in_sizes[0] / 2;
    const int E = in_sizes[1] / 2;
    const int* src = ei;
    const int* dst = ei + E;

    const int B  = 256;
    const int gN = (N + B - 1) / B;

    const int NB = (N + BNODES - 1) / BNODES;
    double mean = (double)E / ((double)N / (double)BNODES);
    unsigned CAP = (unsigned)(mean + 8.0 * sqrt(mean) + 1024.0);
    CAP = (CAP + 1023u) & ~1023u;

    // layout WITH partials (split path)
    char* p = (char*)d_ws;
    float*         m_s   = (float*)p;          p += (((size_t)N * 4 + 255) & ~255ULL);
    unsigned int*  gcur  = (unsigned int*)p;   p += (((size_t)NB * 4 + 255) & ~255ULL);
    unsigned char* cls_s = (unsigned char*)p;  p += (((size_t)N + 255) & ~255ULL);
    char* base_after = p;
    unsigned int*  part    = (unsigned int*)p; // aliased f32/u32 partials
    char* p_split = p + (((size_t)NB * SPLIT * BNODES * 4 + 255) & ~255ULL);
    unsigned int*  gsorted_split = (unsigned int*)p_split;
    size_t need_split = (size_t)(p_split - (char*)d_ws) + (size_t)NB * CAP * 4ULL;

    unsigned int*  gsorted_basic = (unsigned int*)base_after;
    size_t need_basic = (size_t)(base_after - (char*)d_ws) + (size_t)NB * CAP * 4ULL;

    if (ws_size >= need_split && N <= (1 << 20) && NB <= NBINS) {
        const int gP = (E + CHUNK - 1) / CHUNK;
        k_prep2<<<gN, B, 0, stream>>>((const float2*)x, W, m_s, gcur, N, NB, CAP);
        k_permute<<<gP, PTHREADS, 0, stream>>>(src, dst, gsorted_split, gcur, E);
        k_agg1s<<<NB * SPLIT, 512, 0, stream>>>(gsorted_split, gcur, m_s, (float*)part, CAP);
        k_comb1<<<gN, B, 0, stream>>>((const float*)part, cls_s, N);
        k_agg2s<<<NB * SPLIT, 512, 0, stream>>>(gsorted_split, gcur, cls_s, part, CAP);
        k_comb2<<<gN, B, 0, stream>>>(part, W, fw, out, N);
    } else if (ws_size >= need_basic && N <= (1 << 20) && NB <= NBINS) {
        const int gP = (E + CHUNK - 1) / CHUNK;
        k_prep2<<<gN, B, 0, stream>>>((const float2*)x, W, m_s, gcur, N, NB, CAP);
        k_permute<<<gP, PTHREADS, 0, stream>>>(src, dst, gsorted_basic, gcur, E);
        k_agg1<<<NB, 1024, 0, stream>>>(gsorted_basic, gcur, m_s, cls_s, N, CAP);
        k_agg2<<<NB, 1024, 0, stream>>>(gsorted_basic, gcur, cls_s, W, fw, out, N, CAP);
    } else {
        char* q = (char*)d_ws;
        unsigned char* cls = (unsigned char*)q;  q += (((size_t)N + 255) & ~255ULL);
        float*         m   = (float*)q;          q += (((size_t)N * 4 + 255) & ~255ULL);
        float*         y   = (float*)q;          q += (((size_t)N * 4 + 255) & ~255ULL);
        unsigned int*  pk  = (unsigned int*)q;
        const int gE = (E / 8 + B - 1) / B + 1;
        k_prep<<<gN, B, 0, stream>>>((const float2*)x, W, m, y, pk, N);
        k_scatter1<<<gE, B, 0, stream>>>(src, dst, m, y, E);
        k_classify<<<gN, B, 0, stream>>>(y, cls, N);
        k_scatter2<<<gE, B, 0, stream>>>(src, dst, cls, pk, E);
        k_final<<<gN, B, 0, stream>>>(pk, W, fw, out, N);
    }
}